// Round 5
// baseline (46.976 us; speedup 1.0000x reference)
//
#include <hip/hip_runtime.h>
#include <hip/hip_fp16.h>

#define D_DIM 4096
#define H_DIM 4096
#define HB 16                 // rows (h) per block; 64B v-line granularity per block
#define BLK 1024              // 16 waves; wave wv owns row h0+wv
#define NBLK (H_DIM / HB)     // 256 blocks = 1 per CU
#define TILE 512              // scan tile: 8 floats per lane
#define NTL (D_DIM / TILE)    // 8 tiles

__device__ __forceinline__ float fast_sigmoid(float a) {
    return __builtin_amdgcn_rcpf(1.0f + __expf(-a));
}

__device__ __forceinline__ float2 h2_to_f2(unsigned u) {
    union { unsigned u; __half2 h; } cvt;
    cvt.u = u;
    return __half22float2(cvt.h);
}

// ONE barrier total. Phase 1: each wave scans its full row into a 128 KB fp16
// LDS tile (no inter-wave sync needed). Phase 2: each thread dots 4 columns
// of the LDS tile against v rows (deep MLP, no sync). Partials to ws.
template <bool ATOMIC>
__global__ __launch_bounds__(BLK, 4) void nade_main_kernel(
    const float* __restrict__ x,
    const float* __restrict__ w,
    const float* __restrict__ v,
    const float* __restrict__ c,
    float* __restrict__ part)
{
    __shared__ __half S[HB][D_DIM];   // 16 x 4096 fp16 = 128 KB

    const int tid  = threadIdx.x;
    const int wv   = tid >> 6;
    const int lane = tid & 63;
    const int h0   = blockIdx.x * HB;

    // ---------------- Phase 1: scan (no barriers) ----------------
    const float* wrow = w + (size_t)(h0 + wv) * D_DIM + 8 * lane;
    float carry = c[h0 + wv];

    float4 wA0 = *reinterpret_cast<const float4*>(wrow + 0 * TILE);
    float4 wA1 = *reinterpret_cast<const float4*>(wrow + 0 * TILE + 4);
    float4 wB0 = *reinterpret_cast<const float4*>(wrow + 1 * TILE);
    float4 wB1 = *reinterpret_cast<const float4*>(wrow + 1 * TILE + 4);

    auto scan_tile = [&](int t, float4 w0, float4 w1) {
        const float* xp = x + t * TILE + 8 * lane;
        float4 x0 = *reinterpret_cast<const float4*>(xp);
        float4 x1 = *reinterpret_cast<const float4*>(xp + 4);
        float p0 = w0.x * x0.x, p1 = w0.y * x0.y, p2 = w0.z * x0.z, p3 = w0.w * x0.w;
        float p4 = w1.x * x1.x, p5 = w1.y * x1.y, p6 = w1.z * x1.z, p7 = w1.w * x1.w;
        float s8 = ((p0 + p1) + (p2 + p3)) + ((p4 + p5) + (p6 + p7));
        float incl = s8;
        #pragma unroll
        for (int off = 1; off < 64; off <<= 1) {
            float tv = __shfl_up(incl, off, 64);
            incl += (lane >= off) ? tv : 0.0f;
        }
        float tot = __shfl(incl, 63, 64);
        float a = carry + incl - s8;          // pre-activation of lane's col 0
        float sg0 = fast_sigmoid(a); a += p0;
        float sg1 = fast_sigmoid(a); a += p1;
        float sg2 = fast_sigmoid(a); a += p2;
        float sg3 = fast_sigmoid(a); a += p3;
        float sg4 = fast_sigmoid(a); a += p4;
        float sg5 = fast_sigmoid(a); a += p5;
        float sg6 = fast_sigmoid(a); a += p6;
        float sg7 = fast_sigmoid(a);
        carry += tot;
        union { __half2 h2[4]; uint4 u; } P;
        P.h2[0] = __floats2half2_rn(sg0, sg1);
        P.h2[1] = __floats2half2_rn(sg2, sg3);
        P.h2[2] = __floats2half2_rn(sg4, sg5);
        P.h2[3] = __floats2half2_rn(sg6, sg7);
        *reinterpret_cast<uint4*>(&S[wv][t * TILE + 8 * lane]) = P.u;  // b128, conflict-free
    };

    scan_tile(0, wA0, wA1);
    wA0 = *reinterpret_cast<const float4*>(wrow + 2 * TILE);
    wA1 = *reinterpret_cast<const float4*>(wrow + 2 * TILE + 4);
    scan_tile(1, wB0, wB1);
    wB0 = *reinterpret_cast<const float4*>(wrow + 3 * TILE);
    wB1 = *reinterpret_cast<const float4*>(wrow + 3 * TILE + 4);
    scan_tile(2, wA0, wA1);
    wA0 = *reinterpret_cast<const float4*>(wrow + 4 * TILE);
    wA1 = *reinterpret_cast<const float4*>(wrow + 4 * TILE + 4);
    scan_tile(3, wB0, wB1);
    wB0 = *reinterpret_cast<const float4*>(wrow + 5 * TILE);
    wB1 = *reinterpret_cast<const float4*>(wrow + 5 * TILE + 4);
    scan_tile(4, wA0, wA1);
    wA0 = *reinterpret_cast<const float4*>(wrow + 6 * TILE);
    wA1 = *reinterpret_cast<const float4*>(wrow + 6 * TILE + 4);
    scan_tile(5, wB0, wB1);
    wB0 = *reinterpret_cast<const float4*>(wrow + 7 * TILE);
    wB1 = *reinterpret_cast<const float4*>(wrow + 7 * TILE + 4);
    scan_tile(6, wA0, wA1);
    scan_tile(7, wB0, wB1);

    __syncthreads();   // the ONLY barrier

    // ---------------- Phase 2: reduce (no barriers) ----------------
    // thread t owns columns i0..i0+3; reads S columns + 4 full 64B v lines.
    const int i0 = 4 * tid;

    uint2 sr[16];
    #pragma unroll
    for (int h = 0; h < 16; ++h)
        sr[h] = *reinterpret_cast<const uint2*>(&S[h][i0]);

    const float* vp = v + (size_t)i0 * H_DIM + h0;
    float acc0 = 0.0f, acc1 = 0.0f, acc2 = 0.0f, acc3 = 0.0f;

    {   // rows i0, i0+1  (use .x halves: columns i0, i0+1)
        float4 vr0[4], vr1[4];
        #pragma unroll
        for (int k = 0; k < 4; ++k) {
            vr0[k] = *reinterpret_cast<const float4*>(vp + 4 * k);
            vr1[k] = *reinterpret_cast<const float4*>(vp + H_DIM + 4 * k);
        }
        #pragma unroll
        for (int k = 0; k < 4; ++k) {
            float2 f0 = h2_to_f2(sr[4 * k + 0].x);
            float2 f1 = h2_to_f2(sr[4 * k + 1].x);
            float2 f2 = h2_to_f2(sr[4 * k + 2].x);
            float2 f3 = h2_to_f2(sr[4 * k + 3].x);
            acc0 += vr0[k].x * f0.x + vr0[k].y * f1.x + vr0[k].z * f2.x + vr0[k].w * f3.x;
            acc1 += vr1[k].x * f0.y + vr1[k].y * f1.y + vr1[k].z * f2.y + vr1[k].w * f3.y;
        }
    }
    {   // rows i0+2, i0+3  (use .y halves: columns i0+2, i0+3)
        float4 vr2[4], vr3[4];
        #pragma unroll
        for (int k = 0; k < 4; ++k) {
            vr2[k] = *reinterpret_cast<const float4*>(vp + 2 * (size_t)H_DIM + 4 * k);
            vr3[k] = *reinterpret_cast<const float4*>(vp + 3 * (size_t)H_DIM + 4 * k);
        }
        #pragma unroll
        for (int k = 0; k < 4; ++k) {
            float2 f0 = h2_to_f2(sr[4 * k + 0].y);
            float2 f1 = h2_to_f2(sr[4 * k + 1].y);
            float2 f2 = h2_to_f2(sr[4 * k + 2].y);
            float2 f3 = h2_to_f2(sr[4 * k + 3].y);
            acc2 += vr2[k].x * f0.x + vr2[k].y * f1.x + vr2[k].z * f2.x + vr2[k].w * f3.x;
            acc3 += vr3[k].x * f0.y + vr3[k].y * f1.y + vr3[k].z * f2.y + vr3[k].w * f3.y;
        }
    }

    if (ATOMIC) {
        atomicAdd(&part[i0 + 0], acc0);
        atomicAdd(&part[i0 + 1], acc1);
        atomicAdd(&part[i0 + 2], acc2);
        atomicAdd(&part[i0 + 3], acc3);
    } else {
        float4 o; o.x = acc0; o.y = acc1; o.z = acc2; o.w = acc3;
        *reinterpret_cast<float4*>(part + (size_t)blockIdx.x * D_DIM + i0) = o;
    }
}

// Grid: D/64 blocks x 1024 threads. Sums the [NBLK][D] partial matrix (coalesced).
__global__ __launch_bounds__(1024, 1) void nade_reduce_kernel(
    const float* __restrict__ part,
    const float* __restrict__ b,
    float* __restrict__ out)
{
    __shared__ float red[16][64];
    const int tid = threadIdx.x;
    const int bg  = tid >> 6;      // wave id 0..15
    const int il  = tid & 63;
    const int i   = blockIdx.x * 64 + il;
    float s = 0.0f;
    #pragma unroll
    for (int j = 0; j < NBLK / 16; ++j)
        s += part[(size_t)(bg * (NBLK / 16) + j) * D_DIM + i];
    red[bg][il] = s;
    __syncthreads();
    if (tid < 64) {
        float t = b[blockIdx.x * 64 + tid];
        #pragma unroll
        for (int j = 0; j < 16; ++j) t += red[j][tid];
        out[blockIdx.x * 64 + tid] = fast_sigmoid(t);
    }
}

__global__ __launch_bounds__(256, 1) void nade_final_atomic(
    const float* __restrict__ logits,
    const float* __restrict__ b,
    float* __restrict__ out)
{
    const int i = blockIdx.x * 256 + threadIdx.x;
    out[i] = fast_sigmoid(logits[i] + b[i]);
}

extern "C" void kernel_launch(void* const* d_in, const int* in_sizes, int n_in,
                              void* d_out, int out_size, void* d_ws, size_t ws_size,
                              hipStream_t stream)
{
    const float* x = (const float*)d_in[0];
    const float* w = (const float*)d_in[1];
    const float* b = (const float*)d_in[2];
    const float* v = (const float*)d_in[3];
    const float* c = (const float*)d_in[4];
    float* out = (float*)d_out;
    float* ws  = (float*)d_ws;

    const size_t need = (size_t)NBLK * D_DIM * sizeof(float);
    if (ws_size >= need) {
        nade_main_kernel<false><<<NBLK, BLK, 0, stream>>>(x, w, v, c, ws);
        nade_reduce_kernel<<<D_DIM / 64, 1024, 0, stream>>>(ws, b, out);
    } else {
        hipMemsetAsync(d_ws, 0, D_DIM * sizeof(float), stream);
        nade_main_kernel<true><<<NBLK, BLK, 0, stream>>>(x, w, v, c, ws);
        nade_final_atomic<<<D_DIM / 256, 256, 0, stream>>>(ws, b, out);
    }
}